// Round 6
// baseline (145.737 us; speedup 1.0000x reference)
//
#include <hip/hip_runtime.h>
#include <math.h>

#define HB 64      // batch
#define HD 1024    // hidden / input dim
#define KS 128     // K-slice per split-K block
#define XS 68      // padded LDS row stride (floats); keeps float4 reads aligned

typedef float f32x4 __attribute__((ext_vector_type(4)));

// ---------------------------------------------------------------------------
// Split-K register-tiled GEMM slice with register prefetch (double-buffered
// through VGPRs): P[b][m0+mj] = sum_{n=k0..k0+KS-1} X[b][n] * W[m][n]
// Block 256 thr, tile 64b x 64m, thread (bx=t>>4, my=t&15) owns 4b x 4m.
// ---------------------------------------------------------------------------
__device__ __forceinline__ void splitk_tile(
    const float* __restrict__ X0, int noff,      // element n read as X0[b*HD + n - noff]
    const float* __restrict__ W, int K,
    int m0, int k0,
    float* __restrict__ P)                       // 65536-float slab
{
    __shared__ __align__(16) float Xs[32][XS];
    __shared__ __align__(16) float Ws[32][XS];
    const int t  = threadIdx.x;
    const int bx = t >> 4;      // 0..15: batch group
    const int my = t & 15;      // 0..15: m group
    float acc[4][4] = {};

    float4 xp[2], wp[2];
    #pragma unroll
    for (int i = 0; i < 2; ++i) {
        int u = t + 256 * i;
        int r = u >> 3, nq = u & 7;
        xp[i] = *(const float4*)&X0[r * HD + (k0 - noff) + nq * 4];
        wp[i] = *(const float4*)&W[(long long)(m0 + r) * K + k0 + nq * 4];
    }

    for (int kc = 0; kc < KS; kc += 32) {
        #pragma unroll
        for (int i = 0; i < 2; ++i) {
            int u = t + 256 * i;
            int r = u >> 3, nq = u & 7;
            Xs[nq * 4 + 0][r] = xp[i].x; Xs[nq * 4 + 1][r] = xp[i].y;
            Xs[nq * 4 + 2][r] = xp[i].z; Xs[nq * 4 + 3][r] = xp[i].w;
            Ws[nq * 4 + 0][r] = wp[i].x; Ws[nq * 4 + 1][r] = wp[i].y;
            Ws[nq * 4 + 2][r] = wp[i].z; Ws[nq * 4 + 3][r] = wp[i].w;
        }
        __syncthreads();
        if (kc + 32 < KS) {
            const int n0 = k0 + kc + 32;
            #pragma unroll
            for (int i = 0; i < 2; ++i) {
                int u = t + 256 * i;
                int r = u >> 3, nq = u & 7;
                xp[i] = *(const float4*)&X0[r * HD + (n0 - noff) + nq * 4];
                wp[i] = *(const float4*)&W[(long long)(m0 + r) * K + n0 + nq * 4];
            }
        }
        #pragma unroll
        for (int n = 0; n < 32; ++n) {
            float4 xv = *(const float4*)&Xs[n][bx * 4];
            float4 wv = *(const float4*)&Ws[n][my * 4];
            float xe[4] = {xv.x, xv.y, xv.z, xv.w};
            float we[4] = {wv.x, wv.y, wv.z, wv.w};
            #pragma unroll
            for (int i = 0; i < 4; ++i)
                #pragma unroll
                for (int j = 0; j < 4; ++j)
                    acc[i][j] = fmaf(xe[i], we[j], acc[i][j]);
        }
        __syncthreads();
    }
    #pragma unroll
    for (int i = 0; i < 4; ++i) {
        float4 o4 = make_float4(acc[i][0], acc[i][1], acc[i][2], acc[i][3]);
        *(float4*)&P[(bx * 4 + i) * HD + m0 + my * 4] = o4;
    }
}

__global__ __launch_bounds__(256) void qkvfi_splitk(
    const float* __restrict__ x, const float* __restrict__ h,
    const float* __restrict__ Wq, const float* __restrict__ Wk,
    const float* __restrict__ Wv, const float* __restrict__ Wf,
    const float* __restrict__ Wi, float* __restrict__ P)
{
    const int gy = blockIdx.y;
    const float* W; int K, split;
    if (gy < 24) {
        int g = gy >> 3; split = gy & 7; K = HD;
        W = (g == 0) ? Wq : (g == 1) ? Wk : Wv;
    } else {
        int tt = gy - 24; int g = tt >> 4; split = tt & 15; K = 2 * HD;
        W = g ? Wi : Wf;
    }
    const int k0 = split * KS;
    const float* X0; int noff;
    if (k0 < HD) { X0 = x; noff = 0; } else { X0 = h; noff = HD; }
    splitk_tile(X0, noff, W, K, blockIdx.x * 64, k0, P + (size_t)gy * (HB * HD));
}

__global__ __launch_bounds__(256) void out_splitk(
    const float* __restrict__ tr, const float* __restrict__ Wo,
    float* __restrict__ P2)
{
    const int split = blockIdx.y;   // 0..7
    splitk_tile(tr, 0, Wo, HD, blockIdx.x * 64, split * KS,
                P2 + (size_t)split * (HB * HD));
}

// Deterministic float4 partial reduction + bias + activation for q/k/v/f/i.
__global__ __launch_bounds__(256) void reduce_qkvfi(
    const float* __restrict__ P,
    const float* __restrict__ bq, const float* __restrict__ bk,
    const float* __restrict__ bv, const float* __restrict__ bfv,
    const float* __restrict__ biv,
    float* __restrict__ q, float* __restrict__ k, float* __restrict__ v,
    float* __restrict__ fg, float* __restrict__ ig)
{
    const int o4 = blockIdx.x * 256 + threadIdx.x;   // float4 units
    const int g  = o4 >> 14;
    const int r4 = o4 & 16383;
    const int m4 = r4 & 255;
    int base, ns, act; const float* bias; float* out;
    switch (g) {
        case 0:  base = 0;  ns = 8;  bias = bq;  out = q;  act = 0; break;
        case 1:  base = 8;  ns = 8;  bias = bk;  out = k;  act = 0; break;
        case 2:  base = 16; ns = 8;  bias = bv;  out = v;  act = 0; break;
        case 3:  base = 24; ns = 16; bias = bfv; out = fg; act = 1; break;
        default: base = 40; ns = 16; bias = biv; out = ig; act = 1; break;
    }
    float4 s = ((const float4*)bias)[m4];
    const float4* P4 = (const float4*)P;
    for (int i = 0; i < ns; ++i) {
        float4 p = P4[(size_t)(base + i) * 16384 + r4];
        s.x += p.x; s.y += p.y; s.z += p.z; s.w += p.w;
    }
    if (act) {
        s.x = 1.0f / (1.0f + expf(-s.x)); s.y = 1.0f / (1.0f + expf(-s.y));
        s.z = 1.0f / (1.0f + expf(-s.z)); s.w = 1.0f / (1.0f + expf(-s.w));
    }
    ((float4*)out)[r4] = s;
}

__global__ __launch_bounds__(256) void reduce_out(
    const float* __restrict__ P2, const float* __restrict__ bo,
    float* __restrict__ hnew)
{
    const int o4 = blockIdx.x * 256 + threadIdx.x;   // 0..16383
    const int m4 = o4 & 255;
    float4 s = ((const float4*)bo)[m4];
    const float4* P4 = (const float4*)P2;
    #pragma unroll
    for (int i = 0; i < 8; ++i) {
        float4 p = P4[(size_t)i * 16384 + o4];
        s.x += p.x; s.y += p.y; s.z += p.z; s.w += p.w;
    }
    ((float4*)hnew)[o4] = s;
}

// ---------------------------------------------------------------------------
// Fused C update + readout (the HBM-roofline kernel, 537 MB of traffic):
//   Cn[b,m,n] = f[b,m]*C[b,m,n] + (i[b,m]*k[b,m])*v[b,n]
//   tr[b,m]   = tanh( sum_n Cn[b,m,n] * q[b,n] )
// Block = 16 consecutive rows of one batch; q[b,:], v[b,:] staged in LDS once
// (q/v VMEM traffic 256 MB -> 32 MB, per-j reads move to the DS pipe).
// 4 rows/wave. NT on the C streams (round-5 A/B: NT is worth ~9 us).
// ---------------------------------------------------------------------------
__global__ __launch_bounds__(256) void update_kernel(
    const float* __restrict__ C,
    const float* __restrict__ q, const float* __restrict__ k,
    const float* __restrict__ v, const float* __restrict__ fg,
    const float* __restrict__ ig,
    float* __restrict__ Cn, float* __restrict__ tr)
{
    __shared__ __align__(16) float qs[HD];
    __shared__ __align__(16) float vs[HD];
    const int t    = threadIdx.x;
    const int lane = t & 63;
    const int wid  = t >> 6;
    const int blk  = blockIdx.x;          // 0..4095
    const int b    = blk >> 6;            // 64 blocks per batch
    const int mt   = blk & 63;            // 16-row tile within batch

    // stage q[b,:], v[b,:] -> LDS (256 float4 each; one per thread)
    ((float4*)qs)[t] = ((const float4*)q)[b * 256 + t];
    ((float4*)vs)[t] = ((const float4*)v)[b * 256 + t];

    const int r0 = b * HD + mt * 16 + wid * 4;   // first of this wave's 4 rows
    float f_[4], ik_[4];
    #pragma unroll
    for (int rr = 0; rr < 4; ++rr) {
        f_[rr]  = fg[r0 + rr];
        ik_[rr] = ig[r0 + rr] * k[r0 + rr];
    }
    __syncthreads();

    const f32x4* C4 = (const f32x4*)C;
    f32x4*       N4 = (f32x4*)Cn;
    const f32x4* q4s = (const f32x4*)qs;
    const f32x4* v4s = (const f32x4*)vs;

    float racc[4] = {0.f, 0.f, 0.f, 0.f};
    #pragma unroll
    for (int j = 0; j < 4; ++j) {
        const int o = lane + 64 * j;      // float4 column 0..255
        f32x4 cc[4];
        #pragma unroll
        for (int rr = 0; rr < 4; ++rr)
            cc[rr] = __builtin_nontemporal_load(&C4[(r0 + rr) * 256 + o]);
        f32x4 v4 = v4s[o];
        f32x4 q4 = q4s[o];
        #pragma unroll
        for (int rr = 0; rr < 4; ++rr) {
            f32x4 nn;
            nn.x = fmaf(f_[rr], cc[rr].x, ik_[rr] * v4.x);
            nn.y = fmaf(f_[rr], cc[rr].y, ik_[rr] * v4.y);
            nn.z = fmaf(f_[rr], cc[rr].z, ik_[rr] * v4.z);
            nn.w = fmaf(f_[rr], cc[rr].w, ik_[rr] * v4.w);
            __builtin_nontemporal_store(nn, &N4[(r0 + rr) * 256 + o]);
            racc[rr] += nn.x * q4.x + nn.y * q4.y + nn.z * q4.z + nn.w * q4.w;
        }
    }
    #pragma unroll
    for (int off = 32; off; off >>= 1) {
        #pragma unroll
        for (int rr = 0; rr < 4; ++rr)
            racc[rr] += __shfl_xor(racc[rr], off);
    }
    if (lane == 0) {
        #pragma unroll
        for (int rr = 0; rr < 4; ++rr)
            tr[r0 + rr] = tanhf(racc[rr]);
    }
}

extern "C" void kernel_launch(void* const* d_in, const int* in_sizes, int n_in,
                              void* d_out, int out_size, void* d_ws, size_t ws_size,
                              hipStream_t stream) {
    const float* x  = (const float*)d_in[0];
    const float* h  = (const float*)d_in[1];
    const float* C  = (const float*)d_in[2];
    const float* Wq = (const float*)d_in[3];
    const float* bq = (const float*)d_in[4];
    const float* Wk = (const float*)d_in[5];
    const float* bk = (const float*)d_in[6];
    const float* Wv = (const float*)d_in[7];
    const float* bv = (const float*)d_in[8];
    const float* Wf = (const float*)d_in[9];
    const float* bf = (const float*)d_in[10];
    const float* Wi = (const float*)d_in[11];
    const float* bi = (const float*)d_in[12];
    const float* Wo = (const float*)d_in[13];
    const float* bo = (const float*)d_in[14];

    float* outp = (float*)d_out;
    float* hnew = outp;                    // [B,HD]
    float* Cn   = outp + HB * HD;          // [B,HD,HD]

    const size_t SL = (size_t)HB * HD;     // 65536
    float* ws = (float*)d_ws;
    float* q  = ws + 0 * SL;
    float* k  = ws + 1 * SL;
    float* v  = ws + 2 * SL;
    float* fg = ws + 3 * SL;
    float* ig = ws + 4 * SL;
    float* tr = ws + 5 * SL;
    float* P  = ws + 6 * SL;               // 56 slabs
    float* P2 = ws + 62 * SL;              // 8 slabs

    qkvfi_splitk<<<dim3(16, 56), 256, 0, stream>>>(x, h, Wq, Wk, Wv, Wf, Wi, P);
    reduce_qkvfi<<<dim3(320), 256, 0, stream>>>(P, bq, bk, bv, bf, bi,
                                                q, k, v, fg, ig);
    update_kernel<<<dim3((HB * HD) / 16), 256, 0, stream>>>(
        C, q, k, v, fg, ig, Cn, tr);
    out_splitk<<<dim3(16, 8), 256, 0, stream>>>(tr, Wo, P2);
    reduce_out<<<dim3(64), 256, 0, stream>>>(P2, bo, hnew);
}

// Round 8
// 135.963 us; speedup vs baseline: 1.0719x; 1.0719x over previous
//
#include <hip/hip_runtime.h>
#include <math.h>

#define HB 64      // batch
#define HD 1024    // hidden / input dim
#define KS 128     // K-slice per split-K block

typedef float f32x4  __attribute__((ext_vector_type(4)));
typedef short bf16x8 __attribute__((ext_vector_type(8)));

// f32 -> bf16 (RNE) in-register
__device__ __forceinline__ unsigned short f2bf(float f) {
    unsigned int u = __float_as_uint(f);
    u += 0x7fffu + ((u >> 16) & 1u);
    return (unsigned short)(u >> 16);
}
__device__ __forceinline__ float bf2f(unsigned short h) {
    unsigned int u = ((unsigned int)h) << 16;
    return __uint_as_float(u);
}

// Load 8 consecutive f32; split each into hi/lo bf16 (x = hi + lo + O(2^-16 x)).
__device__ __forceinline__ void ldfrag2(const float* __restrict__ p,
                                        bf16x8& hi, bf16x8& lo) {
    float4 a = *(const float4*)p;
    float4 b = *(const float4*)(p + 4);
    float e[8] = {a.x, a.y, a.z, a.w, b.x, b.y, b.z, b.w};
    #pragma unroll
    for (int i = 0; i < 8; ++i) {
        unsigned short h = f2bf(e[i]);
        hi[i] = (short)h;
        lo[i] = (short)f2bf(e[i] - bf2f(h));
    }
}

// ---------------------------------------------------------------------------
// MFMA split-K GEMM slice (bf16x3 pseudo-fp32):
//   P[b][m0+mj] = sum_{n=k0..k0+KS-1} X[b][n]*W[m][n]
// Block 256 thr = 4 waves; wave w owns m-subtile [m0+16w, +16), all 64 b.
// mfma_f32_16x16x32_bf16; acc += Xhi*Whi + Xhi*Wlo + Xlo*Whi (f32 acc).
// Fragments direct from global (32B/lane), in-reg f32->bf16 split.
// k-packing per lane: k = 8*(lane>>4)+i (any consistent A/B k-perm is valid);
// row/col = lane&15; D: col(m)=lane&15, row(b)=(lane>>4)*4+reg (m89-verified;
// R7 bench confirmed layout: error was 0.318 = precision, not layout).
// ---------------------------------------------------------------------------
__device__ __forceinline__ void mfma_tile(
    const float* __restrict__ X0, int noff,
    const float* __restrict__ W, int K,
    int m0, int k0,
    float* __restrict__ P)
{
    const int t     = threadIdx.x;
    const int w     = t >> 6;
    const int l     = t & 63;
    const int row16 = l & 15;
    const int g     = l >> 4;
    const int mbase = m0 + w * 16;

    f32x4 acc[4] = {};
    #pragma unroll
    for (int kk = 0; kk < 4; ++kk) {
        const int kabs = k0 + kk * 32 + g * 8;
        bf16x8 wh, wl;
        ldfrag2(&W[(long long)(mbase + row16) * K + kabs], wh, wl);
        #pragma unroll
        for (int bs = 0; bs < 4; ++bs) {
            bf16x8 xh, xl;
            ldfrag2(&X0[(bs * 16 + row16) * HD + kabs - noff], xh, xl);
            acc[bs] = __builtin_amdgcn_mfma_f32_16x16x32_bf16(xh, wh, acc[bs], 0, 0, 0);
            acc[bs] = __builtin_amdgcn_mfma_f32_16x16x32_bf16(xh, wl, acc[bs], 0, 0, 0);
            acc[bs] = __builtin_amdgcn_mfma_f32_16x16x32_bf16(xl, wh, acc[bs], 0, 0, 0);
        }
    }
    #pragma unroll
    for (int bs = 0; bs < 4; ++bs)
        #pragma unroll
        for (int r = 0; r < 4; ++r)
            P[(bs * 16 + g * 4 + r) * HD + mbase + row16] = acc[bs][r];
}

// grid.x = 16 m-tiles; grid.y = 56 (gemm,split) units:
//   gy 0..23 : q/k/v (8 splits each, K=1024); gy 24..55 : f/i (16 splits, K=2048)
__global__ __launch_bounds__(256) void qkvfi_mfma(
    const float* __restrict__ x, const float* __restrict__ h,
    const float* __restrict__ Wq, const float* __restrict__ Wk,
    const float* __restrict__ Wv, const float* __restrict__ Wf,
    const float* __restrict__ Wi, float* __restrict__ P)
{
    const int gy = blockIdx.y;
    const float* W; int K, split;
    if (gy < 24) {
        int g = gy >> 3; split = gy & 7; K = HD;
        W = (g == 0) ? Wq : (g == 1) ? Wk : Wv;
    } else {
        int tt = gy - 24; int g = tt >> 4; split = tt & 15; K = 2 * HD;
        W = g ? Wi : Wf;
    }
    const int k0 = split * KS;
    const float* X0; int noff;
    if (k0 < HD) { X0 = x; noff = 0; } else { X0 = h; noff = HD; }
    mfma_tile(X0, noff, W, K, blockIdx.x * 64, k0, P + (size_t)gy * (HB * HD));
}

__global__ __launch_bounds__(256) void out_mfma(
    const float* __restrict__ tr, const float* __restrict__ Wo,
    float* __restrict__ P2)
{
    const int split = blockIdx.y;   // 0..7
    mfma_tile(tr, 0, Wo, HD, blockIdx.x * 64, split * KS,
              P2 + (size_t)split * (HB * HD));
}

// Deterministic float4 partial reduction + bias + activation for q/k/v/f/i.
__global__ __launch_bounds__(256) void reduce_qkvfi(
    const float* __restrict__ P,
    const float* __restrict__ bq, const float* __restrict__ bk,
    const float* __restrict__ bv, const float* __restrict__ bfv,
    const float* __restrict__ biv,
    float* __restrict__ q, float* __restrict__ k, float* __restrict__ v,
    float* __restrict__ fg, float* __restrict__ ig)
{
    const int o4 = blockIdx.x * 256 + threadIdx.x;   // float4 units
    const int g  = o4 >> 14;
    const int r4 = o4 & 16383;
    const int m4 = r4 & 255;
    int base, ns, act; const float* bias; float* out;
    switch (g) {
        case 0:  base = 0;  ns = 8;  bias = bq;  out = q;  act = 0; break;
        case 1:  base = 8;  ns = 8;  bias = bk;  out = k;  act = 0; break;
        case 2:  base = 16; ns = 8;  bias = bv;  out = v;  act = 0; break;
        case 3:  base = 24; ns = 16; bias = bfv; out = fg; act = 1; break;
        default: base = 40; ns = 16; bias = biv; out = ig; act = 1; break;
    }
    float4 s = ((const float4*)bias)[m4];
    const float4* P4 = (const float4*)P;
    for (int i = 0; i < ns; ++i) {
        float4 p = P4[(size_t)(base + i) * 16384 + r4];
        s.x += p.x; s.y += p.y; s.z += p.z; s.w += p.w;
    }
    if (act) {
        s.x = 1.0f / (1.0f + expf(-s.x)); s.y = 1.0f / (1.0f + expf(-s.y));
        s.z = 1.0f / (1.0f + expf(-s.z)); s.w = 1.0f / (1.0f + expf(-s.w));
    }
    ((float4*)out)[r4] = s;
}

__global__ __launch_bounds__(256) void reduce_out(
    const float* __restrict__ P2, const float* __restrict__ bo,
    float* __restrict__ hnew)
{
    const int o4 = blockIdx.x * 256 + threadIdx.x;   // 0..16383
    const int m4 = o4 & 255;
    float4 s = ((const float4*)bo)[m4];
    const float4* P4 = (const float4*)P2;
    #pragma unroll
    for (int i = 0; i < 8; ++i) {
        float4 p = P4[(size_t)i * 16384 + o4];
        s.x += p.x; s.y += p.y; s.z += p.z; s.w += p.w;
    }
    ((float4*)hnew)[o4] = s;
}

// ---------------------------------------------------------------------------
// Fused C update + readout (R3-exact — best measured config):
//   Cn[b,m,n] = f[b,m]*C[b,m,n] + (i[b,m]*k[b,m])*v[b,n]
//   tr[b,m]   = tanh( sum_n Cn[b,m,n] * q[b,n] )
// One wave per (b,m) row; NT on C streams (R5 A/B: removing NT costs ~9 us).
// ---------------------------------------------------------------------------
__global__ __launch_bounds__(256) void update_kernel(
    const float* __restrict__ C,
    const float* __restrict__ q, const float* __restrict__ k,
    const float* __restrict__ v, const float* __restrict__ fg,
    const float* __restrict__ ig,
    float* __restrict__ Cn, float* __restrict__ tr)
{
    const int wid  = threadIdx.x >> 6;
    const int lane = threadIdx.x & 63;
    const int row  = blockIdx.x * 4 + wid;      // 0 .. B*HD-1
    const int b    = row >> 10;
    const int m    = row & (HD - 1);

    const float fm  = fg[b * HD + m];
    const float ikm = ig[b * HD + m] * k[b * HD + m];

    const f32x4*  C4 = (const f32x4*)C;
    const float4* V4 = (const float4*)v;
    const float4* Q4 = (const float4*)q;
    f32x4*        N4 = (f32x4*)Cn;

    const int base  = row * (HD / 4);
    const int vbase = b * (HD / 4);

    float racc = 0.f;
    #pragma unroll
    for (int j = 0; j < 4; ++j) {
        int o = lane + 64 * j;
        f32x4 c4 = __builtin_nontemporal_load(&C4[base + o]);
        float4 v4 = V4[vbase + o];
        float4 q4 = Q4[vbase + o];
        f32x4 cn;
        cn.x = fmaf(fm, c4.x, ikm * v4.x);
        cn.y = fmaf(fm, c4.y, ikm * v4.y);
        cn.z = fmaf(fm, c4.z, ikm * v4.z);
        cn.w = fmaf(fm, c4.w, ikm * v4.w);
        __builtin_nontemporal_store(cn, &N4[base + o]);
        racc += cn.x * q4.x + cn.y * q4.y + cn.z * q4.z + cn.w * q4.w;
    }
    #pragma unroll
    for (int off = 32; off; off >>= 1) racc += __shfl_xor(racc, off);
    if (lane == 0) tr[row] = tanhf(racc);
}

extern "C" void kernel_launch(void* const* d_in, const int* in_sizes, int n_in,
                              void* d_out, int out_size, void* d_ws, size_t ws_size,
                              hipStream_t stream) {
    const float* x  = (const float*)d_in[0];
    const float* h  = (const float*)d_in[1];
    const float* C  = (const float*)d_in[2];
    const float* Wq = (const float*)d_in[3];
    const float* bq = (const float*)d_in[4];
    const float* Wk = (const float*)d_in[5];
    const float* bk = (const float*)d_in[6];
    const float* Wv = (const float*)d_in[7];
    const float* bv = (const float*)d_in[8];
    const float* Wf = (const float*)d_in[9];
    const float* bf = (const float*)d_in[10];
    const float* Wi = (const float*)d_in[11];
    const float* bi = (const float*)d_in[12];
    const float* Wo = (const float*)d_in[13];
    const float* bo = (const float*)d_in[14];

    float* outp = (float*)d_out;
    float* hnew = outp;                    // [B,HD]
    float* Cn   = outp + HB * HD;          // [B,HD,HD]

    const size_t SL = (size_t)HB * HD;     // 65536
    float* ws = (float*)d_ws;
    float* q  = ws + 0 * SL;
    float* k  = ws + 1 * SL;
    float* v  = ws + 2 * SL;
    float* fg = ws + 3 * SL;
    float* ig = ws + 4 * SL;
    float* tr = ws + 5 * SL;
    float* P  = ws + 6 * SL;               // 56 slabs
    float* P2 = ws + 62 * SL;              // 8 slabs

    qkvfi_mfma<<<dim3(16, 56), 256, 0, stream>>>(x, h, Wq, Wk, Wv, Wf, Wi, P);
    reduce_qkvfi<<<dim3(320), 256, 0, stream>>>(P, bq, bk, bv, bf, bi,
                                                q, k, v, fg, ig);
    update_kernel<<<dim3((HB * HD) / 4), 256, 0, stream>>>(
        C, q, k, v, fg, ig, Cn, tr);
    out_mfma<<<dim3(16, 8), 256, 0, stream>>>(tr, Wo, P2);
    reduce_out<<<dim3(64), 256, 0, stream>>>(P2, bo, hnew);
}

// Round 9
// 126.566 us; speedup vs baseline: 1.1515x; 1.0742x over previous
//
#include <hip/hip_runtime.h>
#include <math.h>

#define HB 64      // batch
#define HD 1024    // hidden / input dim
#define KS 128     // K-slice per split-K block
#define XS 68      // padded LDS row stride (floats); keeps float4 reads aligned

typedef float f32x4 __attribute__((ext_vector_type(4)));

// ---------------------------------------------------------------------------
// Split-K register-tiled GEMM slice (R3-exact — measured best front chain):
//   P[b][m0+mj] = sum_{n=k0..k0+KS-1} X[b][n] * W[m][n]
// Block 256 thr, tile 64b x 64m, thread (bx=t&15, my=t>>4) owns 4b x 4m.
// ---------------------------------------------------------------------------
__device__ __forceinline__ void splitk_tile(
    const float* __restrict__ X0, int noff,
    const float* __restrict__ W, int K,
    int m0, int k0,
    float* __restrict__ P)
{
    __shared__ __align__(16) float Xs[32][XS];
    __shared__ __align__(16) float Ws[32][XS];
    const int t  = threadIdx.x;
    const int bx = t & 15;
    const int my = t >> 4;
    float acc[4][4] = {};

    for (int kc = 0; kc < KS; kc += 32) {
        const int n0 = k0 + kc;
        #pragma unroll
        for (int i = 0; i < 2; ++i) {
            int u = t + 256 * i;
            int b = u >> 3, nq = u & 7;
            float4 xv = *(const float4*)&X0[b * HD + (n0 - noff) + nq * 4];
            Xs[nq * 4 + 0][b] = xv.x; Xs[nq * 4 + 1][b] = xv.y;
            Xs[nq * 4 + 2][b] = xv.z; Xs[nq * 4 + 3][b] = xv.w;
        }
        #pragma unroll
        for (int i = 0; i < 2; ++i) {
            int u = t + 256 * i;
            int mm = u >> 3, nq = u & 7;
            float4 wv = *(const float4*)&W[(long long)(m0 + mm) * K + n0 + nq * 4];
            Ws[nq * 4 + 0][mm] = wv.x; Ws[nq * 4 + 1][mm] = wv.y;
            Ws[nq * 4 + 2][mm] = wv.z; Ws[nq * 4 + 3][mm] = wv.w;
        }
        __syncthreads();
        #pragma unroll
        for (int n = 0; n < 32; ++n) {
            float4 xv = *(const float4*)&Xs[n][bx * 4];
            float4 wv = *(const float4*)&Ws[n][my * 4];
            float xe[4] = {xv.x, xv.y, xv.z, xv.w};
            float we[4] = {wv.x, wv.y, wv.z, wv.w};
            #pragma unroll
            for (int i = 0; i < 4; ++i)
                #pragma unroll
                for (int j = 0; j < 4; ++j)
                    acc[i][j] = fmaf(xe[i], we[j], acc[i][j]);
        }
        __syncthreads();
    }
    #pragma unroll
    for (int i = 0; i < 4; ++i)
        #pragma unroll
        for (int j = 0; j < 4; ++j)
            P[(bx * 4 + i) * HD + m0 + my * 4 + j] = acc[i][j];
}

__global__ __launch_bounds__(256) void qkvfi_splitk(
    const float* __restrict__ x, const float* __restrict__ h,
    const float* __restrict__ Wq, const float* __restrict__ Wk,
    const float* __restrict__ Wv, const float* __restrict__ Wf,
    const float* __restrict__ Wi, float* __restrict__ P)
{
    const int gy = blockIdx.y;
    const float* W; int K, split;
    if (gy < 24) {
        int g = gy >> 3; split = gy & 7; K = HD;
        W = (g == 0) ? Wq : (g == 1) ? Wk : Wv;
    } else {
        int tt = gy - 24; int g = tt >> 4; split = tt & 15; K = 2 * HD;
        W = g ? Wi : Wf;
    }
    const int k0 = split * KS;
    const float* X0; int noff;
    if (k0 < HD) { X0 = x; noff = 0; } else { X0 = h; noff = HD; }
    splitk_tile(X0, noff, W, K, blockIdx.x * 64, k0, P + (size_t)gy * (HB * HD));
}

__global__ __launch_bounds__(256) void out_splitk(
    const float* __restrict__ tr, const float* __restrict__ Wo,
    float* __restrict__ P2)
{
    const int split = blockIdx.y;   // 0..7
    splitk_tile(tr, 0, Wo, HD, blockIdx.x * 64, split * KS,
                P2 + (size_t)split * (HB * HD));
}

// Deterministic partial reduction + bias + activation for q/k/v/f/i (R3-exact).
__global__ __launch_bounds__(256) void reduce_qkvfi(
    const float* __restrict__ P,
    const float* __restrict__ bq, const float* __restrict__ bk,
    const float* __restrict__ bv, const float* __restrict__ bfv,
    const float* __restrict__ biv,
    float* __restrict__ q, float* __restrict__ k, float* __restrict__ v,
    float* __restrict__ fg, float* __restrict__ ig)
{
    const int o = blockIdx.x * 256 + threadIdx.x;   // 0..327679
    const int g = o >> 16;
    const int rem = o & 65535;
    const int m = rem & (HD - 1);
    int base, ns, act; const float* bias; float* out;
    switch (g) {
        case 0:  base = 0;  ns = 8;  bias = bq;  out = q;  act = 0; break;
        case 1:  base = 8;  ns = 8;  bias = bk;  out = k;  act = 0; break;
        case 2:  base = 16; ns = 8;  bias = bv;  out = v;  act = 0; break;
        case 3:  base = 24; ns = 16; bias = bfv; out = fg; act = 1; break;
        default: base = 40; ns = 16; bias = biv; out = ig; act = 1; break;
    }
    float s = bias[m];
    for (int i = 0; i < ns; ++i) s += P[(size_t)(base + i) * 65536 + rem];
    if (act) s = 1.0f / (1.0f + expf(-s));
    out[rem] = s;
}

__global__ __launch_bounds__(256) void reduce_out(
    const float* __restrict__ P2, const float* __restrict__ bo,
    float* __restrict__ hnew)
{
    const int o = blockIdx.x * 256 + threadIdx.x;   // 0..65535
    const int m = o & (HD - 1);
    float s = bo[m];
    #pragma unroll
    for (int i = 0; i < 8; ++i) s += P2[(size_t)i * 65536 + o];
    hnew[o] = s;
}

// ---------------------------------------------------------------------------
// Fused C update + readout. R3-exact structure (1 row/wave, NT C streams,
// interleaved load/compute/store, o = lane+64j); SINGLE delta vs R3:
// q[b,:] and v[b,:] staged in LDS once per block (all 4 rows of a block share
// the same b), removing 2 of the 3 per-j VMEM load streams.
// ---------------------------------------------------------------------------
__global__ __launch_bounds__(256) void update_kernel(
    const float* __restrict__ C,
    const float* __restrict__ q, const float* __restrict__ k,
    const float* __restrict__ v, const float* __restrict__ fg,
    const float* __restrict__ ig,
    float* __restrict__ Cn, float* __restrict__ tr)
{
    __shared__ __align__(16) float qs[HD];
    __shared__ __align__(16) float vs[HD];
    const int t    = threadIdx.x;
    const int wid  = t >> 6;
    const int lane = t & 63;
    const int row  = blockIdx.x * 4 + wid;      // 0 .. B*HD-1
    const int b    = row >> 10;                 // same for all 4 rows (4|1024)
    const int m    = row & (HD - 1);

    // stage q[b,:], v[b,:] -> LDS (256 float4 each; one per thread)
    ((float4*)qs)[t] = ((const float4*)q)[b * 256 + t];
    ((float4*)vs)[t] = ((const float4*)v)[b * 256 + t];

    const float fm  = fg[b * HD + m];
    const float ikm = ig[b * HD + m] * k[b * HD + m];
    __syncthreads();

    const f32x4* C4  = (const f32x4*)C;
    const f32x4* V4  = (const f32x4*)vs;
    const f32x4* Q4  = (const f32x4*)qs;
    f32x4*       N4  = (f32x4*)Cn;

    const int base = row * (HD / 4);

    float racc = 0.f;
    #pragma unroll
    for (int j = 0; j < 4; ++j) {
        int o = lane + 64 * j;
        f32x4 c4 = __builtin_nontemporal_load(&C4[base + o]);
        f32x4 v4 = V4[o];
        f32x4 q4 = Q4[o];
        f32x4 cn;
        cn.x = fmaf(fm, c4.x, ikm * v4.x);
        cn.y = fmaf(fm, c4.y, ikm * v4.y);
        cn.z = fmaf(fm, c4.z, ikm * v4.z);
        cn.w = fmaf(fm, c4.w, ikm * v4.w);
        __builtin_nontemporal_store(cn, &N4[base + o]);
        racc += cn.x * q4.x + cn.y * q4.y + cn.z * q4.z + cn.w * q4.w;
    }
    #pragma unroll
    for (int off = 32; off; off >>= 1) racc += __shfl_xor(racc, off);
    if (lane == 0) tr[row] = tanhf(racc);
}

extern "C" void kernel_launch(void* const* d_in, const int* in_sizes, int n_in,
                              void* d_out, int out_size, void* d_ws, size_t ws_size,
                              hipStream_t stream) {
    const float* x  = (const float*)d_in[0];
    const float* h  = (const float*)d_in[1];
    const float* C  = (const float*)d_in[2];
    const float* Wq = (const float*)d_in[3];
    const float* bq = (const float*)d_in[4];
    const float* Wk = (const float*)d_in[5];
    const float* bk = (const float*)d_in[6];
    const float* Wv = (const float*)d_in[7];
    const float* bv = (const float*)d_in[8];
    const float* Wf = (const float*)d_in[9];
    const float* bf = (const float*)d_in[10];
    const float* Wi = (const float*)d_in[11];
    const float* bi = (const float*)d_in[12];
    const float* Wo = (const float*)d_in[13];
    const float* bo = (const float*)d_in[14];

    float* outp = (float*)d_out;
    float* hnew = outp;                    // [B,HD]
    float* Cn   = outp + HB * HD;          // [B,HD,HD]

    const size_t SL = (size_t)HB * HD;     // 65536
    float* ws = (float*)d_ws;
    float* q  = ws + 0 * SL;
    float* k  = ws + 1 * SL;
    float* v  = ws + 2 * SL;
    float* fg = ws + 3 * SL;
    float* ig = ws + 4 * SL;
    float* tr = ws + 5 * SL;
    float* P  = ws + 6 * SL;               // 56 slabs
    float* P2 = ws + 62 * SL;              // 8 slabs

    qkvfi_splitk<<<dim3(16, 56), 256, 0, stream>>>(x, h, Wq, Wk, Wv, Wf, Wi, P);
    reduce_qkvfi<<<dim3(1280), 256, 0, stream>>>(P, bq, bk, bv, bf, bi,
                                                 q, k, v, fg, ig);
    update_kernel<<<dim3((HB * HD) / 4), 256, 0, stream>>>(
        C, q, k, v, fg, ig, Cn, tr);
    out_splitk<<<dim3(16, 8), 256, 0, stream>>>(tr, Wo, P2);
    reduce_out<<<dim3(256), 256, 0, stream>>>(P2, bo, hnew);
}

// Round 10
// 124.950 us; speedup vs baseline: 1.1664x; 1.0129x over previous
//
#include <hip/hip_runtime.h>
#include <math.h>

#define HB 64      // batch
#define HD 1024    // hidden / input dim
#define KSF 256    // K-slice per split-K block (front chain)
#define KSB 128    // K-slice (back chain: 128 keeps 128 blocks, latency-safe)
#define XS 68      // padded LDS row stride (floats)

typedef float f32x4 __attribute__((ext_vector_type(4)));

// ---------------------------------------------------------------------------
// Split-K register-tiled GEMM slice with register prefetch:
//   P[b][m0+mj] = sum_{n=k0..k0+KS-1} X[b][n] * W[m][n]
// Block 256 thr, tile 64b x 64m, thread (bx=t&15, my=t>>4) owns 4b x 4m.
// ---------------------------------------------------------------------------
template<int KS>
__device__ __forceinline__ void splitk_tile(
    const float* __restrict__ X0, int noff,
    const float* __restrict__ W, int K,
    int m0, int k0,
    float* __restrict__ P)
{
    __shared__ __align__(16) float Xs[32][XS];
    __shared__ __align__(16) float Ws[32][XS];
    const int t  = threadIdx.x;
    const int bx = t & 15;
    const int my = t >> 4;
    float acc[4][4] = {};

    float4 xp[2], wp[2];
    #pragma unroll
    for (int i = 0; i < 2; ++i) {
        int u = t + 256 * i;
        int r = u >> 3, nq = u & 7;
        xp[i] = *(const float4*)&X0[r * HD + (k0 - noff) + nq * 4];
        wp[i] = *(const float4*)&W[(long long)(m0 + r) * K + k0 + nq * 4];
    }

    for (int kc = 0; kc < KS; kc += 32) {
        #pragma unroll
        for (int i = 0; i < 2; ++i) {
            int u = t + 256 * i;
            int r = u >> 3, nq = u & 7;
            Xs[nq * 4 + 0][r] = xp[i].x; Xs[nq * 4 + 1][r] = xp[i].y;
            Xs[nq * 4 + 2][r] = xp[i].z; Xs[nq * 4 + 3][r] = xp[i].w;
            Ws[nq * 4 + 0][r] = wp[i].x; Ws[nq * 4 + 1][r] = wp[i].y;
            Ws[nq * 4 + 2][r] = wp[i].z; Ws[nq * 4 + 3][r] = wp[i].w;
        }
        __syncthreads();
        if (kc + 32 < KS) {
            const int n0 = k0 + kc + 32;
            #pragma unroll
            for (int i = 0; i < 2; ++i) {
                int u = t + 256 * i;
                int r = u >> 3, nq = u & 7;
                xp[i] = *(const float4*)&X0[r * HD + (n0 - noff) + nq * 4];
                wp[i] = *(const float4*)&W[(long long)(m0 + r) * K + n0 + nq * 4];
            }
        }
        #pragma unroll
        for (int n = 0; n < 32; ++n) {
            float4 xv = *(const float4*)&Xs[n][bx * 4];
            float4 wv = *(const float4*)&Ws[n][my * 4];
            float xe[4] = {xv.x, xv.y, xv.z, xv.w};
            float we[4] = {wv.x, wv.y, wv.z, wv.w};
            #pragma unroll
            for (int i = 0; i < 4; ++i)
                #pragma unroll
                for (int j = 0; j < 4; ++j)
                    acc[i][j] = fmaf(xe[i], we[j], acc[i][j]);
        }
        __syncthreads();
    }
    #pragma unroll
    for (int i = 0; i < 4; ++i) {
        float4 o4 = make_float4(acc[i][0], acc[i][1], acc[i][2], acc[i][3]);
        *(float4*)&P[(bx * 4 + i) * HD + m0 + my * 4] = o4;
    }
}

// grid.x = 16 m-tiles; grid.y = 28 (gemm,split) units, KS=256:
//   gy 0..11 : q/k/v (4 splits each, K=1024); gy 12..27 : f/i (8 splits, K=2048)
__global__ __launch_bounds__(256) void qkvfi_splitk(
    const float* __restrict__ x, const float* __restrict__ h,
    const float* __restrict__ Wq, const float* __restrict__ Wk,
    const float* __restrict__ Wv, const float* __restrict__ Wf,
    const float* __restrict__ Wi, float* __restrict__ P)
{
    const int gy = blockIdx.y;
    const float* W; int K, split;
    if (gy < 12) {
        int g = gy >> 2; split = gy & 3; K = HD;
        W = (g == 0) ? Wq : (g == 1) ? Wk : Wv;
    } else {
        int tt = gy - 12; int g = tt >> 3; split = tt & 7; K = 2 * HD;
        W = g ? Wi : Wf;
    }
    const int k0 = split * KSF;
    const float* X0; int noff;
    if (k0 < HD) { X0 = x; noff = 0; } else { X0 = h; noff = HD; }
    splitk_tile<KSF>(X0, noff, W, K, blockIdx.x * 64, k0,
                     P + (size_t)gy * (HB * HD));
}

__global__ __launch_bounds__(256) void out_splitk(
    const float* __restrict__ tr, const float* __restrict__ Wo,
    float* __restrict__ P2)
{
    const int split = blockIdx.y;   // 0..7
    splitk_tile<KSB>(tr, 0, Wo, HD, blockIdx.x * 64, split * KSB,
                     P2 + (size_t)split * (HB * HD));
}

// Deterministic float4 partial reduction + bias + activation for q/k/v/f/i.
// Slab bases (KS=256): q=0(ns4), k=4(ns4), v=8(ns4), f=12(ns8), i=20(ns8).
__global__ __launch_bounds__(256) void reduce_qkvfi(
    const float* __restrict__ P,
    const float* __restrict__ bq, const float* __restrict__ bk,
    const float* __restrict__ bv, const float* __restrict__ bfv,
    const float* __restrict__ biv,
    float* __restrict__ q, float* __restrict__ k, float* __restrict__ v,
    float* __restrict__ fg, float* __restrict__ ig)
{
    const int o4 = blockIdx.x * 256 + threadIdx.x;   // float4 units, 0..81919
    const int g  = o4 >> 14;
    const int r4 = o4 & 16383;
    const int m4 = r4 & 255;
    int base, ns, act; const float* bias; float* out;
    switch (g) {
        case 0:  base = 0;  ns = 4; bias = bq;  out = q;  act = 0; break;
        case 1:  base = 4;  ns = 4; bias = bk;  out = k;  act = 0; break;
        case 2:  base = 8;  ns = 4; bias = bv;  out = v;  act = 0; break;
        case 3:  base = 12; ns = 8; bias = bfv; out = fg; act = 1; break;
        default: base = 20; ns = 8; bias = biv; out = ig; act = 1; break;
    }
    float4 s = ((const float4*)bias)[m4];
    const float4* P4 = (const float4*)P;
    for (int i = 0; i < ns; ++i) {
        float4 p = P4[(size_t)(base + i) * 16384 + r4];
        s.x += p.x; s.y += p.y; s.z += p.z; s.w += p.w;
    }
    if (act) {
        s.x = 1.0f / (1.0f + expf(-s.x)); s.y = 1.0f / (1.0f + expf(-s.y));
        s.z = 1.0f / (1.0f + expf(-s.z)); s.w = 1.0f / (1.0f + expf(-s.w));
    }
    ((float4*)out)[r4] = s;
}

__global__ __launch_bounds__(256) void reduce_out(
    const float* __restrict__ P2, const float* __restrict__ bo,
    float* __restrict__ hnew)
{
    const int o4 = blockIdx.x * 256 + threadIdx.x;   // 0..16383
    const int m4 = o4 & 255;
    float4 s = ((const float4*)bo)[m4];
    const float4* P4 = (const float4*)P2;
    #pragma unroll
    for (int i = 0; i < 8; ++i) {
        float4 p = P4[(size_t)i * 16384 + o4];
        s.x += p.x; s.y += p.y; s.z += p.z; s.w += p.w;
    }
    ((float4*)hnew)[o4] = s;
}

// ---------------------------------------------------------------------------
// Fused C update + readout (R9-exact — best measured config, 126.6 us):
//   Cn[b,m,n] = f[b,m]*C[b,m,n] + (i[b,m]*k[b,m])*v[b,n]
//   tr[b,m]   = tanh( sum_n Cn[b,m,n] * q[b,n] )
// 1 row/wave, NT C streams, q/v staged in LDS once per block.
// ---------------------------------------------------------------------------
__global__ __launch_bounds__(256) void update_kernel(
    const float* __restrict__ C,
    const float* __restrict__ q, const float* __restrict__ k,
    const float* __restrict__ v, const float* __restrict__ fg,
    const float* __restrict__ ig,
    float* __restrict__ Cn, float* __restrict__ tr)
{
    __shared__ __align__(16) float qs[HD];
    __shared__ __align__(16) float vs[HD];
    const int t    = threadIdx.x;
    const int wid  = t >> 6;
    const int lane = t & 63;
    const int row  = blockIdx.x * 4 + wid;      // 0 .. B*HD-1
    const int b    = row >> 10;                 // same for all 4 rows (4|1024)
    const int m    = row & (HD - 1);

    ((float4*)qs)[t] = ((const float4*)q)[b * 256 + t];
    ((float4*)vs)[t] = ((const float4*)v)[b * 256 + t];

    const float fm  = fg[b * HD + m];
    const float ikm = ig[b * HD + m] * k[b * HD + m];
    __syncthreads();

    const f32x4* C4 = (const f32x4*)C;
    const f32x4* V4 = (const f32x4*)vs;
    const f32x4* Q4 = (const f32x4*)qs;
    f32x4*       N4 = (f32x4*)Cn;

    const int base = row * (HD / 4);

    float racc = 0.f;
    #pragma unroll
    for (int j = 0; j < 4; ++j) {
        int o = lane + 64 * j;
        f32x4 c4 = __builtin_nontemporal_load(&C4[base + o]);
        f32x4 v4 = V4[o];
        f32x4 q4 = Q4[o];
        f32x4 cn;
        cn.x = fmaf(fm, c4.x, ikm * v4.x);
        cn.y = fmaf(fm, c4.y, ikm * v4.y);
        cn.z = fmaf(fm, c4.z, ikm * v4.z);
        cn.w = fmaf(fm, c4.w, ikm * v4.w);
        __builtin_nontemporal_store(cn, &N4[base + o]);
        racc += cn.x * q4.x + cn.y * q4.y + cn.z * q4.z + cn.w * q4.w;
    }
    #pragma unroll
    for (int off = 32; off; off >>= 1) racc += __shfl_xor(racc, off);
    if (lane == 0) tr[row] = tanhf(racc);
}

extern "C" void kernel_launch(void* const* d_in, const int* in_sizes, int n_in,
                              void* d_out, int out_size, void* d_ws, size_t ws_size,
                              hipStream_t stream) {
    const float* x  = (const float*)d_in[0];
    const float* h  = (const float*)d_in[1];
    const float* C  = (const float*)d_in[2];
    const float* Wq = (const float*)d_in[3];
    const float* bq = (const float*)d_in[4];
    const float* Wk = (const float*)d_in[5];
    const float* bk = (const float*)d_in[6];
    const float* Wv = (const float*)d_in[7];
    const float* bv = (const float*)d_in[8];
    const float* Wf = (const float*)d_in[9];
    const float* bf = (const float*)d_in[10];
    const float* Wi = (const float*)d_in[11];
    const float* bi = (const float*)d_in[12];
    const float* Wo = (const float*)d_in[13];
    const float* bo = (const float*)d_in[14];

    float* outp = (float*)d_out;
    float* hnew = outp;                    // [B,HD]
    float* Cn   = outp + HB * HD;          // [B,HD,HD]

    const size_t SL = (size_t)HB * HD;     // 65536
    float* ws = (float*)d_ws;
    float* q  = ws + 0 * SL;
    float* k  = ws + 1 * SL;
    float* v  = ws + 2 * SL;
    float* fg = ws + 3 * SL;
    float* ig = ws + 4 * SL;
    float* tr = ws + 5 * SL;
    float* P  = ws + 6 * SL;               // 28 slabs (KS=256)
    float* P2 = ws + 34 * SL;              // 8 slabs  (KS=128)

    qkvfi_splitk<<<dim3(16, 28), 256, 0, stream>>>(x, h, Wq, Wk, Wv, Wf, Wi, P);
    reduce_qkvfi<<<dim3(320), 256, 0, stream>>>(P, bq, bk, bv, bf, bi,
                                                q, k, v, fg, ig);
    update_kernel<<<dim3((HB * HD) / 4), 256, 0, stream>>>(
        C, q, k, v, fg, ig, Cn, tr);
    out_splitk<<<dim3(16, 8), 256, 0, stream>>>(tr, Wo, P2);
    reduce_out<<<dim3(64), 256, 0, stream>>>(P2, bo, hnew);
}

// Round 11
// 122.639 us; speedup vs baseline: 1.1883x; 1.0189x over previous
//
#include <hip/hip_runtime.h>
#include <math.h>

#define HB 64      // batch
#define HD 1024    // hidden / input dim
#define KSF 256    // K-slice per split-K block (front chain)
#define KSB 128    // K-slice (back chain: 128 keeps 128 blocks, latency-safe)
#define XS 68      // padded LDS row stride (floats)

typedef float f32x4 __attribute__((ext_vector_type(4)));

// ---------------------------------------------------------------------------
// Split-K register-tiled GEMM slice with register prefetch:
//   P[b][m0+mj] = sum_{n=k0..k0+KS-1} X[b][n] * W[m][n]
// Block 256 thr, tile 64b x 64m, thread (bx=t&15, my=t>>4) owns 4b x 4m.
// ---------------------------------------------------------------------------
template<int KS>
__device__ __forceinline__ void splitk_tile(
    const float* __restrict__ X0, int noff,
    const float* __restrict__ W, int K,
    int m0, int k0,
    float* __restrict__ P)
{
    __shared__ __align__(16) float Xs[32][XS];
    __shared__ __align__(16) float Ws[32][XS];
    const int t  = threadIdx.x;
    const int bx = t & 15;
    const int my = t >> 4;
    float acc[4][4] = {};

    float4 xp[2], wp[2];
    #pragma unroll
    for (int i = 0; i < 2; ++i) {
        int u = t + 256 * i;
        int r = u >> 3, nq = u & 7;
        xp[i] = *(const float4*)&X0[r * HD + (k0 - noff) + nq * 4];
        wp[i] = *(const float4*)&W[(long long)(m0 + r) * K + k0 + nq * 4];
    }

    for (int kc = 0; kc < KS; kc += 32) {
        #pragma unroll
        for (int i = 0; i < 2; ++i) {
            int u = t + 256 * i;
            int r = u >> 3, nq = u & 7;
            Xs[nq * 4 + 0][r] = xp[i].x; Xs[nq * 4 + 1][r] = xp[i].y;
            Xs[nq * 4 + 2][r] = xp[i].z; Xs[nq * 4 + 3][r] = xp[i].w;
            Ws[nq * 4 + 0][r] = wp[i].x; Ws[nq * 4 + 1][r] = wp[i].y;
            Ws[nq * 4 + 2][r] = wp[i].z; Ws[nq * 4 + 3][r] = wp[i].w;
        }
        __syncthreads();
        if (kc + 32 < KS) {
            const int n0 = k0 + kc + 32;
            #pragma unroll
            for (int i = 0; i < 2; ++i) {
                int u = t + 256 * i;
                int r = u >> 3, nq = u & 7;
                xp[i] = *(const float4*)&X0[r * HD + (n0 - noff) + nq * 4];
                wp[i] = *(const float4*)&W[(long long)(m0 + r) * K + n0 + nq * 4];
            }
        }
        #pragma unroll
        for (int n = 0; n < 32; ++n) {
            float4 xv = *(const float4*)&Xs[n][bx * 4];
            float4 wv = *(const float4*)&Ws[n][my * 4];
            float xe[4] = {xv.x, xv.y, xv.z, xv.w};
            float we[4] = {wv.x, wv.y, wv.z, wv.w};
            #pragma unroll
            for (int i = 0; i < 4; ++i)
                #pragma unroll
                for (int j = 0; j < 4; ++j)
                    acc[i][j] = fmaf(xe[i], we[j], acc[i][j]);
        }
        __syncthreads();
    }
    #pragma unroll
    for (int i = 0; i < 4; ++i) {
        float4 o4 = make_float4(acc[i][0], acc[i][1], acc[i][2], acc[i][3]);
        *(float4*)&P[(bx * 4 + i) * HD + m0 + my * 4] = o4;
    }
}

// grid.x = 16 m-tiles; grid.y = 28 (gemm,split) units, KS=256:
//   gy 0..11 : q/k/v (4 splits each, K=1024); gy 12..27 : f/i (8 splits, K=2048)
__global__ __launch_bounds__(256) void qkvfi_splitk(
    const float* __restrict__ x, const float* __restrict__ h,
    const float* __restrict__ Wq, const float* __restrict__ Wk,
    const float* __restrict__ Wv, const float* __restrict__ Wf,
    const float* __restrict__ Wi, float* __restrict__ P)
{
    const int gy = blockIdx.y;
    const float* W; int K, split;
    if (gy < 12) {
        int g = gy >> 2; split = gy & 3; K = HD;
        W = (g == 0) ? Wq : (g == 1) ? Wk : Wv;
    } else {
        int tt = gy - 12; int g = tt >> 3; split = tt & 7; K = 2 * HD;
        W = g ? Wi : Wf;
    }
    const int k0 = split * KSF;
    const float* X0; int noff;
    if (k0 < HD) { X0 = x; noff = 0; } else { X0 = h; noff = HD; }
    splitk_tile<KSF>(X0, noff, W, K, blockIdx.x * 64, k0,
                     P + (size_t)gy * (HB * HD));
}

__global__ __launch_bounds__(256) void out_splitk(
    const float* __restrict__ tr, const float* __restrict__ Wo,
    float* __restrict__ P2)
{
    const int split = blockIdx.y;   // 0..7
    splitk_tile<KSB>(tr, 0, Wo, HD, blockIdx.x * 64, split * KSB,
                     P2 + (size_t)split * (HB * HD));
}

// Deterministic float4 partial reduction + bias + activation for q/k/v/f/i.
// Slab bases (KS=256): q=0(ns4), k=4(ns4), v=8(ns4), f=12(ns8), i=20(ns8).
__global__ __launch_bounds__(256) void reduce_qkvfi(
    const float* __restrict__ P,
    const float* __restrict__ bq, const float* __restrict__ bk,
    const float* __restrict__ bv, const float* __restrict__ bfv,
    const float* __restrict__ biv,
    float* __restrict__ q, float* __restrict__ k, float* __restrict__ v,
    float* __restrict__ fg, float* __restrict__ ig)
{
    const int o4 = blockIdx.x * 256 + threadIdx.x;   // float4 units, 0..81919
    const int g  = o4 >> 14;
    const int r4 = o4 & 16383;
    const int m4 = r4 & 255;
    int base, ns, act; const float* bias; float* out;
    switch (g) {
        case 0:  base = 0;  ns = 4; bias = bq;  out = q;  act = 0; break;
        case 1:  base = 4;  ns = 4; bias = bk;  out = k;  act = 0; break;
        case 2:  base = 8;  ns = 4; bias = bv;  out = v;  act = 0; break;
        case 3:  base = 12; ns = 8; bias = bfv; out = fg; act = 1; break;
        default: base = 20; ns = 8; bias = biv; out = ig; act = 1; break;
    }
    float4 s = ((const float4*)bias)[m4];
    const float4* P4 = (const float4*)P;
    for (int i = 0; i < ns; ++i) {
        float4 p = P4[(size_t)(base + i) * 16384 + r4];
        s.x += p.x; s.y += p.y; s.z += p.z; s.w += p.w;
    }
    if (act) {
        s.x = 1.0f / (1.0f + expf(-s.x)); s.y = 1.0f / (1.0f + expf(-s.y));
        s.z = 1.0f / (1.0f + expf(-s.z)); s.w = 1.0f / (1.0f + expf(-s.w));
    }
    ((float4*)out)[r4] = s;
}

__global__ __launch_bounds__(256) void reduce_out(
    const float* __restrict__ P2, const float* __restrict__ bo,
    float* __restrict__ hnew)
{
    const int o4 = blockIdx.x * 256 + threadIdx.x;   // 0..16383
    const int m4 = o4 & 255;
    float4 s = ((const float4*)bo)[m4];
    const float4* P4 = (const float4*)P2;
    #pragma unroll
    for (int i = 0; i < 8; ++i) {
        float4 p = P4[(size_t)i * 16384 + o4];
        s.x += p.x; s.y += p.y; s.z += p.z; s.w += p.w;
    }
    ((float4*)hnew)[o4] = s;
}

// ---------------------------------------------------------------------------
// Fused C update + readout. R10 structure; SINGLE delta: NT on the C LOAD
// only, PLAIN stores for Cn (memset counter-evidence: plain write stream
// sustains 7.0 TB/s; NT-store bypasses L2 write coalescing).
//   Cn[b,m,n] = f[b,m]*C[b,m,n] + (i[b,m]*k[b,m])*v[b,n]
//   tr[b,m]   = tanh( sum_n Cn[b,m,n] * q[b,n] )
// ---------------------------------------------------------------------------
__global__ __launch_bounds__(256) void update_kernel(
    const float* __restrict__ C,
    const float* __restrict__ q, const float* __restrict__ k,
    const float* __restrict__ v, const float* __restrict__ fg,
    const float* __restrict__ ig,
    float* __restrict__ Cn, float* __restrict__ tr)
{
    __shared__ __align__(16) float qs[HD];
    __shared__ __align__(16) float vs[HD];
    const int t    = threadIdx.x;
    const int wid  = t >> 6;
    const int lane = t & 63;
    const int row  = blockIdx.x * 4 + wid;      // 0 .. B*HD-1
    const int b    = row >> 10;                 // same for all 4 rows (4|1024)
    const int m    = row & (HD - 1);

    ((float4*)qs)[t] = ((const float4*)q)[b * 256 + t];
    ((float4*)vs)[t] = ((const float4*)v)[b * 256 + t];

    const float fm  = fg[b * HD + m];
    const float ikm = ig[b * HD + m] * k[b * HD + m];
    __syncthreads();

    const f32x4* C4 = (const f32x4*)C;
    const f32x4* V4 = (const f32x4*)vs;
    const f32x4* Q4 = (const f32x4*)qs;
    f32x4*       N4 = (f32x4*)Cn;

    const int base = row * (HD / 4);

    float racc = 0.f;
    #pragma unroll
    for (int j = 0; j < 4; ++j) {
        int o = lane + 64 * j;
        f32x4 c4 = __builtin_nontemporal_load(&C4[base + o]);
        f32x4 v4 = V4[o];
        f32x4 q4 = Q4[o];
        f32x4 cn;
        cn.x = fmaf(fm, c4.x, ikm * v4.x);
        cn.y = fmaf(fm, c4.y, ikm * v4.y);
        cn.z = fmaf(fm, c4.z, ikm * v4.z);
        cn.w = fmaf(fm, c4.w, ikm * v4.w);
        N4[base + o] = cn;                      // plain cached store
        racc += cn.x * q4.x + cn.y * q4.y + cn.z * q4.z + cn.w * q4.w;
    }
    #pragma unroll
    for (int off = 32; off; off >>= 1) racc += __shfl_xor(racc, off);
    if (lane == 0) tr[row] = tanhf(racc);
}

extern "C" void kernel_launch(void* const* d_in, const int* in_sizes, int n_in,
                              void* d_out, int out_size, void* d_ws, size_t ws_size,
                              hipStream_t stream) {
    const float* x  = (const float*)d_in[0];
    const float* h  = (const float*)d_in[1];
    const float* C  = (const float*)d_in[2];
    const float* Wq = (const float*)d_in[3];
    const float* bq = (const float*)d_in[4];
    const float* Wk = (const float*)d_in[5];
    const float* bk = (const float*)d_in[6];
    const float* Wv = (const float*)d_in[7];
    const float* bv = (const float*)d_in[8];
    const float* Wf = (const float*)d_in[9];
    const float* bf = (const float*)d_in[10];
    const float* Wi = (const float*)d_in[11];
    const float* bi = (const float*)d_in[12];
    const float* Wo = (const float*)d_in[13];
    const float* bo = (const float*)d_in[14];

    float* outp = (float*)d_out;
    float* hnew = outp;                    // [B,HD]
    float* Cn   = outp + HB * HD;          // [B,HD,HD]

    const size_t SL = (size_t)HB * HD;     // 65536
    float* ws = (float*)d_ws;
    float* q  = ws + 0 * SL;
    float* k  = ws + 1 * SL;
    float* v  = ws + 2 * SL;
    float* fg = ws + 3 * SL;
    float* ig = ws + 4 * SL;
    float* tr = ws + 5 * SL;
    float* P  = ws + 6 * SL;               // 28 slabs (KS=256)
    float* P2 = ws + 34 * SL;              // 8 slabs  (KS=128)

    qkvfi_splitk<<<dim3(16, 28), 256, 0, stream>>>(x, h, Wq, Wk, Wv, Wf, Wi, P);
    reduce_qkvfi<<<dim3(320), 256, 0, stream>>>(P, bq, bk, bv, bf, bi,
                                                q, k, v, fg, ig);
    update_kernel<<<dim3((HB * HD) / 4), 256, 0, stream>>>(
        C, q, k, v, fg, ig, Cn, tr);
    out_splitk<<<dim3(16, 8), 256, 0, stream>>>(tr, Wo, P2);
    reduce_out<<<dim3(64), 256, 0, stream>>>(P2, bo, hnew);
}